// Round 9
// baseline (275.894 us; speedup 1.0000x reference)
//
#include <hip/hip_runtime.h>

#define B 4
#define S 2048
#define D 1024
#define E 8
#define K2 2
#define H 2048              // 2*D
#define NTOK (B * S)        // 8192
#define SPIKE_THR 0.1f
#define EPSV 1e-8f
#define HEAVY_CAP 16        // spiking tokens: ~6 expected; 16 = +4 sigma
#define ACH 64              // stage A chunks: 16 d-rows x H (128 KB each)
#define BCH 64              // stage B chunks: 32 h-rows x D (128 KB each)
#define TGA 2               // token group size, stage A
#define TGB 2               // token group size, stage B

struct TokRec {
    int   i0, i1;
    float p0, p1;
    float denom;
    int   spiked;
    int   pad0, pad1;
};

__device__ __forceinline__ float4 f4_fma(float s, float4 w, float4 a) {
    a.x = fmaf(s, w.x, a.x);
    a.y = fmaf(s, w.y, a.y);
    a.z = fmaf(s, w.z, a.z);
    a.w = fmaf(s, w.w, a.w);
    return a;
}
__device__ __forceinline__ float4 f4_add(float4 a, float4 b) {
    return make_float4(a.x + b.x, a.y + b.y, a.z + b.z, a.w + b.w);
}
__device__ __forceinline__ float f4_get(const float4 v, int i) {
    return (i == 0) ? v.x : (i == 1) ? v.y : (i == 2) ? v.z : v.w;
}

// ---------------------------------------------------------------------------
// Kernel 1: fused z = silu(b1[e]) @ w2[e] + b2[e]  (ballot-compacted nonzero
// rows; b1==0 here -> empty -> z=b2 fast path) + control-counter clear.
// grid E, block 256.
// ---------------------------------------------------------------------------
__global__ __launch_bounds__(256) void z_kernel(
    const float* __restrict__ b1,   // [E][H]
    const float* __restrict__ w2,   // [E][H][D]
    const float* __restrict__ b2,   // [E][D]
    float* __restrict__ z,          // [E][D]
    int* __restrict__ heavyCount,
    int* __restrict__ expCnt,       // [E]
    int* __restrict__ gateDone)
{
    const int e = blockIdx.x;
    const int wave = threadIdx.x >> 6;
    const int lane = threadIdx.x & 63;

    if (e == 0 && threadIdx.x < 32) {
        if (threadIdx.x == 0) *heavyCount = 0;
        if (threadIdx.x == 1) *gateDone = 0;
        if (threadIdx.x >= 2 && threadIdx.x < 2 + E) expCnt[threadIdx.x - 2] = 0;
    }

    __shared__ float nzcoef[256];
    __shared__ short nzrow[256];
    __shared__ int   wcnt[4];

    const int d0 = threadIdx.x * 4;
    float4 acc = make_float4(0.f, 0.f, 0.f, 0.f);

    for (int hc = 0; hc < H / 256; ++hc) {
        const float b = b1[(size_t)e * H + hc * 256 + threadIdx.x];
        const float c = (b != 0.0f) ? (b / (1.0f + expf(-b))) : 0.0f;

        const unsigned long long mask = __ballot(c != 0.0f);
        const int cnt  = __popcll(mask);
        const int rank = __popcll(mask & ((lane == 0) ? 0ull : (~0ull >> (64 - lane))));
        if (lane == 0) wcnt[wave] = cnt;
        __syncthreads();

        int base = 0;
#pragma unroll
        for (int w = 0; w < 4; ++w) base += (w < wave) ? wcnt[w] : 0;
        const int total = wcnt[0] + wcnt[1] + wcnt[2] + wcnt[3];
        if (c != 0.0f) {
            nzcoef[base + rank] = c;
            nzrow[base + rank]  = (short)threadIdx.x;
        }
        __syncthreads();

        for (int j = 0; j < total; ++j) {
            const int row = nzrow[j];
            acc = f4_fma(nzcoef[j],
                         *reinterpret_cast<const float4*>(
                             w2 + ((size_t)e * H + hc * 256 + row) * D + d0),
                         acc);
        }
        __syncthreads();
    }

    const float4 bb = *reinterpret_cast<const float4*>(b2 + (size_t)e * D + d0);
    *reinterpret_cast<float4*>(z + (size_t)e * D + d0) = f4_add(acc, bb);
}

// ---------------------------------------------------------------------------
// Kernel 2: gating + top-2 + softmax + fused non-spiking combine + direct
// expList build (order-independent: every enc has its own accumulator
// downstream, so atomic list order cannot change FP results) + last-block
// fused aux loss (threadfence/done-counter; fixed-order reduce -> determin.)
// ---------------------------------------------------------------------------
__global__ __launch_bounds__(256) void gate_kernel(
    const float* __restrict__ x,
    const float* __restrict__ gate_w,   // [D][E]
    const float* __restrict__ gate_b,   // [E]
    const float* __restrict__ noise,    // [NTOK][E]
    const float* __restrict__ zt,       // [E][D]
    float* __restrict__ outTopi,        // [NTOK][K2]
    float* __restrict__ outFinal,       // [NTOK][D]
    TokRec* __restrict__ rec,
    int* __restrict__ heavyCount,
    int* __restrict__ heavyList,
    int heavyCap,
    float* __restrict__ usagePartial,   // [gridDim.x][E]
    int* __restrict__ expCnt,           // [E]
    int* __restrict__ expList,          // [E][64]
    int* __restrict__ gateDone,
    float* __restrict__ auxOut)
{
    const int wave = threadIdx.x >> 6;
    const int lane = threadIdx.x & 63;
    const int t = (blockIdx.x << 2) + wave;

    __shared__ float s_usage[4][E];
    __shared__ int   s_last;

    const float* xrow = x + (size_t)t * D;
    float4 xv[4];
#pragma unroll
    for (int j = 0; j < 4; ++j)
        xv[j] = reinterpret_cast<const float4*>(xrow)[(j << 6) + lane];

    float sum = 0.0f;
#pragma unroll
    for (int j = 0; j < 4; ++j)
        sum += (xv[j].x + xv[j].y) + (xv[j].z + xv[j].w);
#pragma unroll
    for (int off = 32; off > 0; off >>= 1)
        sum += __shfl_xor(sum, off, 64);

    const float mean  = sum * (1.0f / (float)D);
    const bool  spiked = (mean > SPIKE_THR);
    const float denom = sum + EPSV;

    float logit[E];
#pragma unroll
    for (int e = 0; e < E; ++e) logit[e] = 0.0f;

    if (spiked) {
#pragma unroll
        for (int j = 0; j < 4; ++j) {
            const float xs[4] = {xv[j].x, xv[j].y, xv[j].z, xv[j].w};
#pragma unroll
            for (int q = 0; q < 4; ++q) {
                const int d = (j << 8) + (lane << 2) + q;
                const float xn = xs[q] / denom;
                const float4* gp = reinterpret_cast<const float4*>(gate_w + (size_t)d * E);
                const float4 g0 = gp[0];
                const float4 g1 = gp[1];
                logit[0] += xn * g0.x; logit[1] += xn * g0.y;
                logit[2] += xn * g0.z; logit[3] += xn * g0.w;
                logit[4] += xn * g1.x; logit[5] += xn * g1.y;
                logit[6] += xn * g1.z; logit[7] += xn * g1.w;
            }
        }
#pragma unroll
        for (int e = 0; e < E; ++e) {
            float v = logit[e];
#pragma unroll
            for (int off = 32; off > 0; off >>= 1)
                v += __shfl_xor(v, off, 64);
            logit[e] = v;
        }
    }

#pragma unroll
    for (int e = 0; e < E; ++e)
        logit[e] = logit[e] + gate_b[e] + noise[(size_t)t * E + e] * 0.01f;

    // top-2 (lowest-index tie-break)
    int i0 = 0; float v0 = logit[0];
#pragma unroll
    for (int e = 1; e < E; ++e)
        if (logit[e] > v0) { v0 = logit[e]; i0 = e; }
    int i1 = (i0 == 0) ? 1 : 0;
    float v1 = logit[i1];
#pragma unroll
    for (int e = 0; e < E; ++e) {
        if (e == i0 || e == ((i0 == 0) ? 1 : 0)) continue;
        if (logit[e] > v1) { v1 = logit[e]; i1 = e; }
    }

    float pe[E]; float den = 0.0f;
#pragma unroll
    for (int e = 0; e < E; ++e) {
        const float p = (logit[e] >= v1) ? expf(logit[e] - v0) : 0.0f;
        pe[e] = p; den += p;
    }
    float gp[E];
#pragma unroll
    for (int e = 0; e < E; ++e) gp[e] = pe[e] / den;

    int slotB = 0;
    if (lane == 0 && spiked) slotB = atomicAdd(heavyCount, 1);
    slotB = __shfl(slotB, 0, 64);
    const bool fallback = spiked && (slotB >= heavyCap);

    if (lane == 0) {
#pragma unroll
        for (int e = 0; e < E; ++e) s_usage[wave][e] = gp[e];
        outTopi[(size_t)t * K2 + 0] = (float)i0;
        outTopi[(size_t)t * K2 + 1] = (float)i1;
        TokRec r;
        r.i0 = i0; r.i1 = i1;
        r.p0 = gp[i0]; r.p1 = gp[i1];
        r.denom = denom; r.spiked = spiked ? 1 : 0;
        r.pad0 = 0; r.pad1 = 0;
        rec[t] = r;
        if (spiked && slotB < heavyCap) {
            heavyList[slotB] = t;
            const int p0i = atomicAdd(&expCnt[i0], 1);
            expList[i0 * 64 + p0i] = slotB * 2;
            const int p1i = atomicAdd(&expCnt[i1], 1);
            expList[i1 * 64 + p1i] = slotB * 2 + 1;
        }
    }

    if (!spiked || fallback) {
        const float p0 = gp[i0], p1 = gp[i1];
        const float4* z0 = reinterpret_cast<const float4*>(zt + (size_t)i0 * D);
        const float4* z1 = reinterpret_cast<const float4*>(zt + (size_t)i1 * D);
        float4* o = reinterpret_cast<float4*>(outFinal + (size_t)t * D);
#pragma unroll
        for (int j = 0; j < 4; ++j) {
            const float4 a = z0[(j << 6) + lane];
            const float4 b = z1[(j << 6) + lane];
            float4 v;
            v.x = p0 * a.x + p1 * b.x;
            v.y = p0 * a.y + p1 * b.y;
            v.z = p0 * a.z + p1 * b.z;
            v.w = p0 * a.w + p1 * b.w;
            o[(j << 6) + lane] = v;
        }
    }

    __syncthreads();
    if (threadIdx.x < E) {
        const int e = threadIdx.x;
        usagePartial[(size_t)blockIdx.x * E + e] =
            ((s_usage[0][e] + s_usage[1][e]) + s_usage[2][e]) + s_usage[3][e];
    }

    // --- last-block fused aux loss ---
    __threadfence();
    __syncthreads();
    if (threadIdx.x == 0)
        s_last = (atomicAdd(gateDone, 1) == (int)gridDim.x - 1) ? 1 : 0;
    __syncthreads();
    if (s_last) {
        __threadfence();
        __shared__ float s[256][E];
        const int nPart = (int)gridDim.x;
        float acc[E];
#pragma unroll
        for (int e = 0; e < E; ++e) acc[e] = 0.0f;
        for (int i = threadIdx.x; i < nPart; i += 256) {
#pragma unroll
            for (int e = 0; e < E; ++e) acc[e] += usagePartial[(size_t)i * E + e];
        }
#pragma unroll
        for (int e = 0; e < E; ++e) s[threadIdx.x][e] = acc[e];
        __syncthreads();
        for (int stride = 128; stride > 0; stride >>= 1) {
            if (threadIdx.x < stride) {
#pragma unroll
                for (int e = 0; e < E; ++e)
                    s[threadIdx.x][e] += s[threadIdx.x + stride][e];
            }
            __syncthreads();
        }
        if (threadIdx.x == 0) {
            float usage[E]; float tot = 0.0f;
#pragma unroll
            for (int e = 0; e < E; ++e) { usage[e] = s[0][e]; tot += usage[e]; }
            tot += 1e-10f;
            float imp[E]; float m = 0.0f;
#pragma unroll
            for (int e = 0; e < E; ++e) { imp[e] = usage[e] / tot; m += imp[e]; }
            m *= (1.0f / (float)E);
            float var = 0.0f;
#pragma unroll
            for (int e = 0; e < E; ++e) { const float dd = imp[e] - m; var += dd * dd; }
            var *= (1.0f / (float)E);
            auxOut[0] = sqrtf(var) / (m + 1e-10f);
        }
    }
}

// ---------------------------------------------------------------------------
// Kernel 3: heavy stage A, expert-major sequential streaming, TGA=2.
// Block (e,c): streams contiguous 128 KB chunk w1[e][c*16..+16][:] linearly,
// applies to all tokens of expert e. hpart[enc][c][H] (unscaled).
// ---------------------------------------------------------------------------
__global__ __launch_bounds__(256, 1) void heavyA_kernel(
    const float* __restrict__ x,
    const float* __restrict__ w1,   // [E][D][H]
    const int* __restrict__ heavyList,
    const int* __restrict__ expCnt,
    const int* __restrict__ expList,
    float* __restrict__ hpart)      // [2*HEAVY_CAP][ACH][H]
{
    const int e = blockIdx.x;
    const int c = blockIdx.y;
    const int m = expCnt[e];
    if (m == 0) return;
    const int tid4 = threadIdx.x << 2;
    const int d0 = c * 16;
    const float* wbase = w1 + (size_t)e * D * H + (size_t)d0 * H;

    for (int g = 0; g < m; g += TGA) {
        const int mg = (m - g < TGA) ? (m - g) : TGA;
        int enc[TGA];
        float4 xs[TGA][4];
#pragma unroll
        for (int j = 0; j < TGA; ++j) {
            const int jj = (j < mg) ? j : 0;
            enc[j] = expList[e * 64 + g + jj];
            const int t = heavyList[enc[j] >> 1];
            const float4* xp = reinterpret_cast<const float4*>(x + (size_t)t * D + d0);
            xs[j][0] = xp[0]; xs[j][1] = xp[1]; xs[j][2] = xp[2]; xs[j][3] = xp[3];
        }
        float4 acc[TGA][2];
#pragma unroll
        for (int j = 0; j < TGA; ++j) {
            acc[j][0] = make_float4(0.f, 0.f, 0.f, 0.f);
            acc[j][1] = make_float4(0.f, 0.f, 0.f, 0.f);
        }
#pragma unroll
        for (int r4 = 0; r4 < 16; r4 += 4) {
            float4 wv[4][2];
#pragma unroll
            for (int rr = 0; rr < 4; ++rr) {
                const float* wr = wbase + (size_t)(r4 + rr) * H + tid4;
                wv[rr][0] = *reinterpret_cast<const float4*>(wr);
                wv[rr][1] = *reinterpret_cast<const float4*>(wr + 1024);
            }
#pragma unroll
            for (int rr = 0; rr < 4; ++rr) {
#pragma unroll
                for (int j = 0; j < TGA; ++j) {
                    const float s = f4_get(xs[j][r4 >> 2], rr);
                    acc[j][0] = f4_fma(s, wv[rr][0], acc[j][0]);
                    acc[j][1] = f4_fma(s, wv[rr][1], acc[j][1]);
                }
            }
        }
#pragma unroll
        for (int j = 0; j < TGA; ++j) {
            if (j < mg) {
                float* dst = hpart + ((size_t)enc[j] * ACH + c) * H + tid4;
                *reinterpret_cast<float4*>(dst)        = acc[j][0];
                *reinterpret_cast<float4*>(dst + 1024) = acc[j][1];
            }
        }
    }
}

// ---------------------------------------------------------------------------
// Kernel 4: heavy stage B with FUSED hred. Block (e,c) owns h-rows
// [c*32, c*32+32): first reduces hpart over ACH chunks for exactly those rows
// (256-thread split: (j,row,part), 16 chunks each; fixed combine order ->
// deterministic), applies 1/denom + b1 + silu, then streams the contiguous
// 128 KB w2 chunk with h values held in registers. opart[enc][c][D].
// ---------------------------------------------------------------------------
__global__ __launch_bounds__(256, 1) void heavyB_kernel(
    const float* __restrict__ hpart, // [2*HEAVY_CAP][ACH][H]
    const float* __restrict__ w2,    // [E][H][D]
    const float* __restrict__ b1,    // [E][H]
    const TokRec* __restrict__ rec,
    const int* __restrict__ heavyList,
    const int* __restrict__ expCnt,
    const int* __restrict__ expList,
    float* __restrict__ opart)       // [2*HEAVY_CAP][BCH][D]
{
    const int e = blockIdx.x;
    const int c = blockIdx.y;
    const int m = expCnt[e];
    if (m == 0) return;
    const int tid4 = threadIdx.x << 2;
    const int h0 = c * 32;
    const float* wbase = w2 + (size_t)e * H * D + (size_t)h0 * D;

    __shared__ float hp4[TGB][32][4];
    __shared__ float hs[TGB][32];

    for (int g = 0; g < m; g += TGB) {
        const int mg = (m - g < TGB) ? (m - g) : TGB;
        int enc[TGB];
#pragma unroll
        for (int j = 0; j < TGB; ++j)
            enc[j] = expList[e * 64 + g + ((j < mg) ? j : 0)];

        // fused hred: thread = (j, row, part), each sums 16 chunks
        {
            const int j    = threadIdx.x >> 7;         // 0..1
            const int row  = (threadIdx.x >> 2) & 31;  // 0..31
            const int part = threadIdx.x & 3;          // 0..3
            const float* base = hpart + (size_t)enc[j] * ACH * H
                              + (size_t)(part * 16) * H + h0 + row;
            float s = 0.f;
#pragma unroll
            for (int ch = 0; ch < 16; ++ch)
                s += base[(size_t)ch * H];
            hp4[j][row][part] = s;
        }
        __syncthreads();
        if (threadIdx.x < 32 * TGB) {
            const int j = threadIdx.x >> 5;
            const int row = threadIdx.x & 31;
            const TokRec r = rec[heavyList[enc[j] >> 1]];
            const float rd = 1.0f / r.denom;
            float s = ((hp4[j][row][0] + hp4[j][row][1]) +
                       (hp4[j][row][2] + hp4[j][row][3])) * rd
                      + b1[(size_t)e * H + h0 + row];
            hs[j][row] = s / (1.0f + expf(-s));
        }
        __syncthreads();

        // LDS -> registers once; inner loop is then pure global loads + FMA
        float hr0[32], hr1[32];
#pragma unroll
        for (int i = 0; i < 32; ++i) { hr0[i] = hs[0][i]; hr1[i] = hs[1][i]; }

        float4 acc0 = make_float4(0.f, 0.f, 0.f, 0.f);
        float4 acc1 = acc0;
#pragma unroll
        for (int r4 = 0; r4 < 32; r4 += 4) {
            float4 wv[4];
#pragma unroll
            for (int rr = 0; rr < 4; ++rr)
                wv[rr] = *reinterpret_cast<const float4*>(
                             wbase + (size_t)(r4 + rr) * D + tid4);
#pragma unroll
            for (int rr = 0; rr < 4; ++rr) {
                acc0 = f4_fma(hr0[r4 + rr], wv[rr], acc0);
                acc1 = f4_fma(hr1[r4 + rr], wv[rr], acc1);
            }
        }
        if (mg > 0)
            *reinterpret_cast<float4*>(
                opart + ((size_t)enc[0] * BCH + c) * D + tid4) = acc0;
        if (mg > 1)
            *reinterpret_cast<float4*>(
                opart + ((size_t)enc[1] * BCH + c) * D + tid4) = acc1;
        __syncthreads();
    }
}

// ---------------------------------------------------------------------------
// Kernel 5: reduce BCH chunks, + b2, combine p0/p1 -> outFinal[t]
// ---------------------------------------------------------------------------
__global__ __launch_bounds__(256) void outred_kernel(
    const float* __restrict__ opart,
    const float* __restrict__ b2,   // [E][D]
    const TokRec* __restrict__ rec,
    const int* __restrict__ heavyCount,
    const int* __restrict__ heavyList,
    float* __restrict__ outFinal)
{
    int cnt = *heavyCount; if (cnt > HEAVY_CAP) cnt = HEAVY_CAP;
    const int slot = blockIdx.x;
    if (slot >= cnt) return;
    const int t = heavyList[slot];
    const TokRec r = rec[t];
    const int d = threadIdx.x * 4;

    const float* p0b = opart + ((size_t)(slot * 2 + 0)) * BCH * D;
    const float* p1b = opart + ((size_t)(slot * 2 + 1)) * BCH * D;

    float4 s0 = make_float4(0.f, 0.f, 0.f, 0.f);
    float4 s1 = make_float4(0.f, 0.f, 0.f, 0.f);
#pragma unroll 8
    for (int c = 0; c < BCH; ++c) {
        s0 = f4_add(s0, *reinterpret_cast<const float4*>(p0b + (size_t)c * D + d));
        s1 = f4_add(s1, *reinterpret_cast<const float4*>(p1b + (size_t)c * D + d));
    }
    const float4 bb0 = *reinterpret_cast<const float4*>(b2 + (size_t)r.i0 * D + d);
    const float4 bb1 = *reinterpret_cast<const float4*>(b2 + (size_t)r.i1 * D + d);
    float4 v;
    v.x = r.p0 * (s0.x + bb0.x) + r.p1 * (s1.x + bb1.x);
    v.y = r.p0 * (s0.y + bb0.y) + r.p1 * (s1.y + bb1.y);
    v.z = r.p0 * (s0.z + bb0.z) + r.p1 * (s1.z + bb1.z);
    v.w = r.p0 * (s0.w + bb0.w) + r.p1 * (s1.w + bb1.w);
    *reinterpret_cast<float4*>(outFinal + (size_t)t * D + d) = v;
}

// ---------------------------------------------------------------------------
extern "C" void kernel_launch(void* const* d_in, const int* in_sizes, int n_in,
                              void* d_out, int out_size, void* d_ws, size_t ws_size,
                              hipStream_t stream)
{
    const float* x      = (const float*)d_in[0];
    const float* gate_w = (const float*)d_in[1];
    const float* gate_b = (const float*)d_in[2];
    const float* w1     = (const float*)d_in[3];
    const float* b1     = (const float*)d_in[4];
    const float* w2     = (const float*)d_in[5];
    const float* b2     = (const float*)d_in[6];
    const float* noise  = (const float*)d_in[7];

    float* outFinal = (float*)d_out;
    float* outTopi  = outFinal + (size_t)NTOK * D;
    float* outAux   = outTopi + (size_t)NTOK * K2;

    char* ws = (char*)d_ws;
    size_t off = 0;
    int* heavyCount = (int*)(ws + off);            off += 64;
    int* expCnt     = (int*)(ws + off);            off += 64;
    int* gateDone   = (int*)(ws + off);            off += 64;
    int* heavyList  = (int*)(ws + off);            off += 128;
    int* expList    = (int*)(ws + off);            off += sizeof(int) * E * 64;
    off = (off + 255) & ~(size_t)255;
    TokRec* rec = (TokRec*)(ws + off);             off += sizeof(TokRec) * NTOK;
    float* usagePartial = (float*)(ws + off);      off += sizeof(float) * (NTOK / 4) * E;
    float* z = (float*)(ws + off);                 off += sizeof(float) * E * D;
    off = (off + 255) & ~(size_t)255;
    float* hpart = (float*)(ws + off);             off += sizeof(float) * 2 * HEAVY_CAP * ACH * H;
    float* opart = (float*)(ws + off);             off += sizeof(float) * 2 * HEAVY_CAP * BCH * D;

    z_kernel<<<E, 256, 0, stream>>>(b1, w2, b2, z, heavyCount, expCnt, gateDone);
    gate_kernel<<<NTOK / 4, 256, 0, stream>>>(x, gate_w, gate_b, noise, z,
                                              outTopi, outFinal,
                                              rec, heavyCount, heavyList, HEAVY_CAP,
                                              usagePartial, expCnt, expList,
                                              gateDone, outAux);
    heavyA_kernel<<<dim3(E, ACH), 256, 0, stream>>>(
        x, w1, heavyList, expCnt, expList, hpart);
    heavyB_kernel<<<dim3(E, BCH), 256, 0, stream>>>(
        hpart, w2, b1, rec, heavyList, expCnt, expList, opart);
    outred_kernel<<<HEAVY_CAP, 256, 0, stream>>>(
        opart, b2, rec, heavyCount, heavyList, outFinal);
}

// Round 10
// 63.523 us; speedup vs baseline: 4.3432x; 4.3432x over previous
//
#include <hip/hip_runtime.h>

#define B 4
#define S 2048
#define D 1024
#define E 8
#define K2 2
#define H 2048              // 2*D
#define NTOK (B * S)        // 8192
#define SPIKE_THR 0.1f
#define EPSV 1e-8f
#define HEAVY_CAP 16        // spiking tokens: ~6 expected; 16 = +4 sigma
#define ACH 64              // stage A chunks: 16 d-rows x H (128 KB each)
#define BCH 64              // stage B chunks: 32 h-rows x D (128 KB each)
#define TGA 2               // token group size, stage A
#define TGB 2               // token group size, stage B

struct TokRec {
    int   i0, i1;
    float p0, p1;
    float denom;
    int   spiked;
    int   pad0, pad1;
};

__device__ __forceinline__ float4 f4_fma(float s, float4 w, float4 a) {
    a.x = fmaf(s, w.x, a.x);
    a.y = fmaf(s, w.y, a.y);
    a.z = fmaf(s, w.z, a.z);
    a.w = fmaf(s, w.w, a.w);
    return a;
}
__device__ __forceinline__ float4 f4_add(float4 a, float4 b) {
    return make_float4(a.x + b.x, a.y + b.y, a.z + b.z, a.w + b.w);
}
__device__ __forceinline__ float f4_get(const float4 v, int i) {
    return (i == 0) ? v.x : (i == 1) ? v.y : (i == 2) ? v.z : v.w;
}

// ---------------------------------------------------------------------------
// Kernel 1: fused z = silu(b1[e]) @ w2[e] + b2[e]  (ballot-compacted nonzero
// rows; b1==0 here -> empty -> z=b2 fast path) + control-counter clear.
// grid E, block 256.
// ---------------------------------------------------------------------------
__global__ __launch_bounds__(256) void z_kernel(
    const float* __restrict__ b1,   // [E][H]
    const float* __restrict__ w2,   // [E][H][D]
    const float* __restrict__ b2,   // [E][D]
    float* __restrict__ z,          // [E][D]
    int* __restrict__ heavyCount,
    int* __restrict__ expCnt)       // [E]
{
    const int e = blockIdx.x;
    const int wave = threadIdx.x >> 6;
    const int lane = threadIdx.x & 63;

    if (e == 0 && threadIdx.x < 32) {
        if (threadIdx.x == 0) *heavyCount = 0;
        if (threadIdx.x >= 1 && threadIdx.x < 1 + E) expCnt[threadIdx.x - 1] = 0;
    }

    __shared__ float nzcoef[256];
    __shared__ short nzrow[256];
    __shared__ int   wcnt[4];

    const int d0 = threadIdx.x * 4;
    float4 acc = make_float4(0.f, 0.f, 0.f, 0.f);

    for (int hc = 0; hc < H / 256; ++hc) {
        const float b = b1[(size_t)e * H + hc * 256 + threadIdx.x];
        const float c = (b != 0.0f) ? (b / (1.0f + expf(-b))) : 0.0f;

        const unsigned long long mask = __ballot(c != 0.0f);
        const int cnt  = __popcll(mask);
        const int rank = __popcll(mask & ((lane == 0) ? 0ull : (~0ull >> (64 - lane))));
        if (lane == 0) wcnt[wave] = cnt;
        __syncthreads();

        int base = 0;
#pragma unroll
        for (int w = 0; w < 4; ++w) base += (w < wave) ? wcnt[w] : 0;
        const int total = wcnt[0] + wcnt[1] + wcnt[2] + wcnt[3];
        if (c != 0.0f) {
            nzcoef[base + rank] = c;
            nzrow[base + rank]  = (short)threadIdx.x;
        }
        __syncthreads();

        for (int j = 0; j < total; ++j) {
            const int row = nzrow[j];
            acc = f4_fma(nzcoef[j],
                         *reinterpret_cast<const float4*>(
                             w2 + ((size_t)e * H + hc * 256 + row) * D + d0),
                         acc);
        }
        __syncthreads();
    }

    const float4 bb = *reinterpret_cast<const float4*>(b2 + (size_t)e * D + d0);
    *reinterpret_cast<float4*>(z + (size_t)e * D + d0) = f4_add(acc, bb);
}

// ---------------------------------------------------------------------------
// Kernel 2: gating + top-2 + softmax + fused non-spiking combine + direct
// expList build (order-independent downstream). NO device fences.
// ---------------------------------------------------------------------------
__global__ __launch_bounds__(256) void gate_kernel(
    const float* __restrict__ x,
    const float* __restrict__ gate_w,   // [D][E]
    const float* __restrict__ gate_b,   // [E]
    const float* __restrict__ noise,    // [NTOK][E]
    const float* __restrict__ zt,       // [E][D]
    float* __restrict__ outTopi,        // [NTOK][K2]
    float* __restrict__ outFinal,       // [NTOK][D]
    TokRec* __restrict__ rec,
    int* __restrict__ heavyCount,
    int* __restrict__ heavyList,
    int heavyCap,
    float* __restrict__ usagePartial,   // [gridDim.x][E]
    int* __restrict__ expCnt,           // [E]
    int* __restrict__ expList)          // [E][64]
{
    const int wave = threadIdx.x >> 6;
    const int lane = threadIdx.x & 63;
    const int t = (blockIdx.x << 2) + wave;

    __shared__ float s_usage[4][E];

    const float* xrow = x + (size_t)t * D;
    float4 xv[4];
#pragma unroll
    for (int j = 0; j < 4; ++j)
        xv[j] = reinterpret_cast<const float4*>(xrow)[(j << 6) + lane];

    float sum = 0.0f;
#pragma unroll
    for (int j = 0; j < 4; ++j)
        sum += (xv[j].x + xv[j].y) + (xv[j].z + xv[j].w);
#pragma unroll
    for (int off = 32; off > 0; off >>= 1)
        sum += __shfl_xor(sum, off, 64);

    const float mean  = sum * (1.0f / (float)D);
    const bool  spiked = (mean > SPIKE_THR);
    const float denom = sum + EPSV;

    float logit[E];
#pragma unroll
    for (int e = 0; e < E; ++e) logit[e] = 0.0f;

    if (spiked) {
#pragma unroll
        for (int j = 0; j < 4; ++j) {
            const float xs[4] = {xv[j].x, xv[j].y, xv[j].z, xv[j].w};
#pragma unroll
            for (int q = 0; q < 4; ++q) {
                const int d = (j << 8) + (lane << 2) + q;
                const float xn = xs[q] / denom;
                const float4* gp = reinterpret_cast<const float4*>(gate_w + (size_t)d * E);
                const float4 g0 = gp[0];
                const float4 g1 = gp[1];
                logit[0] += xn * g0.x; logit[1] += xn * g0.y;
                logit[2] += xn * g0.z; logit[3] += xn * g0.w;
                logit[4] += xn * g1.x; logit[5] += xn * g1.y;
                logit[6] += xn * g1.z; logit[7] += xn * g1.w;
            }
        }
#pragma unroll
        for (int e = 0; e < E; ++e) {
            float v = logit[e];
#pragma unroll
            for (int off = 32; off > 0; off >>= 1)
                v += __shfl_xor(v, off, 64);
            logit[e] = v;
        }
    }

#pragma unroll
    for (int e = 0; e < E; ++e)
        logit[e] = logit[e] + gate_b[e] + noise[(size_t)t * E + e] * 0.01f;

    // top-2 (lowest-index tie-break)
    int i0 = 0; float v0 = logit[0];
#pragma unroll
    for (int e = 1; e < E; ++e)
        if (logit[e] > v0) { v0 = logit[e]; i0 = e; }
    int i1 = (i0 == 0) ? 1 : 0;
    float v1 = logit[i1];
#pragma unroll
    for (int e = 0; e < E; ++e) {
        if (e == i0 || e == ((i0 == 0) ? 1 : 0)) continue;
        if (logit[e] > v1) { v1 = logit[e]; i1 = e; }
    }

    float pe[E]; float den = 0.0f;
#pragma unroll
    for (int e = 0; e < E; ++e) {
        const float p = (logit[e] >= v1) ? expf(logit[e] - v0) : 0.0f;
        pe[e] = p; den += p;
    }
    float gp[E];
#pragma unroll
    for (int e = 0; e < E; ++e) gp[e] = pe[e] / den;

    int slotB = 0;
    if (lane == 0 && spiked) slotB = atomicAdd(heavyCount, 1);
    slotB = __shfl(slotB, 0, 64);
    const bool fallback = spiked && (slotB >= heavyCap);

    if (lane == 0) {
#pragma unroll
        for (int e = 0; e < E; ++e) s_usage[wave][e] = gp[e];
        outTopi[(size_t)t * K2 + 0] = (float)i0;
        outTopi[(size_t)t * K2 + 1] = (float)i1;
        TokRec r;
        r.i0 = i0; r.i1 = i1;
        r.p0 = gp[i0]; r.p1 = gp[i1];
        r.denom = denom; r.spiked = spiked ? 1 : 0;
        r.pad0 = 0; r.pad1 = 0;
        rec[t] = r;
        if (spiked && slotB < heavyCap) {
            heavyList[slotB] = t;
            const int p0i = atomicAdd(&expCnt[i0], 1);
            expList[i0 * 64 + p0i] = slotB * 2;
            const int p1i = atomicAdd(&expCnt[i1], 1);
            expList[i1 * 64 + p1i] = slotB * 2 + 1;
        }
    }

    if (!spiked || fallback) {
        const float p0 = gp[i0], p1 = gp[i1];
        const float4* z0 = reinterpret_cast<const float4*>(zt + (size_t)i0 * D);
        const float4* z1 = reinterpret_cast<const float4*>(zt + (size_t)i1 * D);
        float4* o = reinterpret_cast<float4*>(outFinal + (size_t)t * D);
#pragma unroll
        for (int j = 0; j < 4; ++j) {
            const float4 a = z0[(j << 6) + lane];
            const float4 b = z1[(j << 6) + lane];
            float4 v;
            v.x = p0 * a.x + p1 * b.x;
            v.y = p0 * a.y + p1 * b.y;
            v.z = p0 * a.z + p1 * b.z;
            v.w = p0 * a.w + p1 * b.w;
            o[(j << 6) + lane] = v;
        }
    }

    __syncthreads();
    if (threadIdx.x < E) {
        const int e = threadIdx.x;
        usagePartial[(size_t)blockIdx.x * E + e] =
            ((s_usage[0][e] + s_usage[1][e]) + s_usage[2][e]) + s_usage[3][e];
    }
}

// ---------------------------------------------------------------------------
// Kernel 3: deterministic usage reduce + aux loss (single small block)
// ---------------------------------------------------------------------------
__global__ __launch_bounds__(256) void aux_kernel(
    const float* __restrict__ usagePartial, int nPart,
    float* __restrict__ auxOut)
{
    __shared__ float s[256][E];
    float acc[E];
#pragma unroll
    for (int e = 0; e < E; ++e) acc[e] = 0.0f;
    for (int i = threadIdx.x; i < nPart; i += 256) {
#pragma unroll
        for (int e = 0; e < E; ++e) acc[e] += usagePartial[(size_t)i * E + e];
    }
#pragma unroll
    for (int e = 0; e < E; ++e) s[threadIdx.x][e] = acc[e];
    __syncthreads();
    for (int stride = 128; stride > 0; stride >>= 1) {
        if (threadIdx.x < stride) {
#pragma unroll
            for (int e = 0; e < E; ++e)
                s[threadIdx.x][e] += s[threadIdx.x + stride][e];
        }
        __syncthreads();
    }
    if (threadIdx.x == 0) {
        float usage[E]; float tot = 0.0f;
#pragma unroll
        for (int e = 0; e < E; ++e) { usage[e] = s[0][e]; tot += usage[e]; }
        tot += 1e-10f;
        float imp[E]; float m = 0.0f;
#pragma unroll
        for (int e = 0; e < E; ++e) { imp[e] = usage[e] / tot; m += imp[e]; }
        m *= (1.0f / (float)E);
        float var = 0.0f;
#pragma unroll
        for (int e = 0; e < E; ++e) { const float dd = imp[e] - m; var += dd * dd; }
        var *= (1.0f / (float)E);
        auxOut[0] = sqrtf(var) / (m + 1e-10f);
    }
}

// ---------------------------------------------------------------------------
// Kernel 4: heavy stage A, expert-major sequential streaming, TGA=2.
// Block (e,c): streams contiguous 128 KB chunk w1[e][c*16..+16][:] linearly,
// applies to all tokens of expert e. hpart[enc][c][H] (unscaled).
// ---------------------------------------------------------------------------
__global__ __launch_bounds__(256, 1) void heavyA_kernel(
    const float* __restrict__ x,
    const float* __restrict__ w1,   // [E][D][H]
    const int* __restrict__ heavyList,
    const int* __restrict__ expCnt,
    const int* __restrict__ expList,
    float* __restrict__ hpart)      // [2*HEAVY_CAP][ACH][H]
{
    const int e = blockIdx.x;
    const int c = blockIdx.y;
    const int m = expCnt[e];
    if (m == 0) return;
    const int tid4 = threadIdx.x << 2;
    const int d0 = c * 16;
    const float* wbase = w1 + (size_t)e * D * H + (size_t)d0 * H;

    for (int g = 0; g < m; g += TGA) {
        const int mg = (m - g < TGA) ? (m - g) : TGA;
        int enc[TGA];
        float4 xs[TGA][4];
#pragma unroll
        for (int j = 0; j < TGA; ++j) {
            const int jj = (j < mg) ? j : 0;
            enc[j] = expList[e * 64 + g + jj];
            const int t = heavyList[enc[j] >> 1];
            const float4* xp = reinterpret_cast<const float4*>(x + (size_t)t * D + d0);
            xs[j][0] = xp[0]; xs[j][1] = xp[1]; xs[j][2] = xp[2]; xs[j][3] = xp[3];
        }
        float4 acc[TGA][2];
#pragma unroll
        for (int j = 0; j < TGA; ++j) {
            acc[j][0] = make_float4(0.f, 0.f, 0.f, 0.f);
            acc[j][1] = make_float4(0.f, 0.f, 0.f, 0.f);
        }
#pragma unroll
        for (int r4 = 0; r4 < 16; r4 += 4) {
            float4 wv[4][2];
#pragma unroll
            for (int rr = 0; rr < 4; ++rr) {
                const float* wr = wbase + (size_t)(r4 + rr) * H + tid4;
                wv[rr][0] = *reinterpret_cast<const float4*>(wr);
                wv[rr][1] = *reinterpret_cast<const float4*>(wr + 1024);
            }
#pragma unroll
            for (int rr = 0; rr < 4; ++rr) {
#pragma unroll
                for (int j = 0; j < TGA; ++j) {
                    const float s = f4_get(xs[j][r4 >> 2], rr);
                    acc[j][0] = f4_fma(s, wv[rr][0], acc[j][0]);
                    acc[j][1] = f4_fma(s, wv[rr][1], acc[j][1]);
                }
            }
        }
#pragma unroll
        for (int j = 0; j < TGA; ++j) {
            if (j < mg) {
                float* dst = hpart + ((size_t)enc[j] * ACH + c) * H + tid4;
                *reinterpret_cast<float4*>(dst)        = acc[j][0];
                *reinterpret_cast<float4*>(dst + 1024) = acc[j][1];
            }
        }
    }
}

// ---------------------------------------------------------------------------
// Kernel 5: heavy stage B with FUSED hred. Block (e,c) owns h-rows
// [c*32, c*32+32): reduces hpart over ACH chunks for those rows (fixed
// order -> deterministic), applies 1/denom + b1 + silu, then streams the
// contiguous 128 KB w2 chunk with h in registers. opart[enc][c][D].
// ---------------------------------------------------------------------------
__global__ __launch_bounds__(256, 1) void heavyB_kernel(
    const float* __restrict__ hpart, // [2*HEAVY_CAP][ACH][H]
    const float* __restrict__ w2,    // [E][H][D]
    const float* __restrict__ b1,    // [E][H]
    const TokRec* __restrict__ rec,
    const int* __restrict__ heavyList,
    const int* __restrict__ expCnt,
    const int* __restrict__ expList,
    float* __restrict__ opart)       // [2*HEAVY_CAP][BCH][D]
{
    const int e = blockIdx.x;
    const int c = blockIdx.y;
    const int m = expCnt[e];
    if (m == 0) return;
    const int tid4 = threadIdx.x << 2;
    const int h0 = c * 32;
    const float* wbase = w2 + (size_t)e * H * D + (size_t)h0 * D;

    __shared__ float hp4[TGB][32][4];
    __shared__ float hs[TGB][32];

    for (int g = 0; g < m; g += TGB) {
        const int mg = (m - g < TGB) ? (m - g) : TGB;
        int enc[TGB];
#pragma unroll
        for (int j = 0; j < TGB; ++j)
            enc[j] = expList[e * 64 + g + ((j < mg) ? j : 0)];

        // fused hred: thread = (j, row, part), each sums 16 chunks
        {
            const int j    = threadIdx.x >> 7;         // 0..1
            const int row  = (threadIdx.x >> 2) & 31;  // 0..31
            const int part = threadIdx.x & 3;          // 0..3
            const float* base = hpart + (size_t)enc[j] * ACH * H
                              + (size_t)(part * 16) * H + h0 + row;
            float s = 0.f;
#pragma unroll
            for (int ch = 0; ch < 16; ++ch)
                s += base[(size_t)ch * H];
            hp4[j][row][part] = s;
        }
        __syncthreads();
        if (threadIdx.x < 32 * TGB) {
            const int j = threadIdx.x >> 5;
            const int row = threadIdx.x & 31;
            const TokRec r = rec[heavyList[enc[j] >> 1]];
            const float rd = 1.0f / r.denom;
            float s = ((hp4[j][row][0] + hp4[j][row][1]) +
                       (hp4[j][row][2] + hp4[j][row][3])) * rd
                      + b1[(size_t)e * H + h0 + row];
            hs[j][row] = s / (1.0f + expf(-s));
        }
        __syncthreads();

        float hr0[32], hr1[32];
#pragma unroll
        for (int i = 0; i < 32; ++i) { hr0[i] = hs[0][i]; hr1[i] = hs[1][i]; }

        float4 acc0 = make_float4(0.f, 0.f, 0.f, 0.f);
        float4 acc1 = acc0;
#pragma unroll
        for (int r4 = 0; r4 < 32; r4 += 4) {
            float4 wv[4];
#pragma unroll
            for (int rr = 0; rr < 4; ++rr)
                wv[rr] = *reinterpret_cast<const float4*>(
                             wbase + (size_t)(r4 + rr) * D + tid4);
#pragma unroll
            for (int rr = 0; rr < 4; ++rr) {
                acc0 = f4_fma(hr0[r4 + rr], wv[rr], acc0);
                acc1 = f4_fma(hr1[r4 + rr], wv[rr], acc1);
            }
        }
        if (mg > 0)
            *reinterpret_cast<float4*>(
                opart + ((size_t)enc[0] * BCH + c) * D + tid4) = acc0;
        if (mg > 1)
            *reinterpret_cast<float4*>(
                opart + ((size_t)enc[1] * BCH + c) * D + tid4) = acc1;
        __syncthreads();
    }
}

// ---------------------------------------------------------------------------
// Kernel 6: reduce BCH chunks, + b2, combine p0/p1 -> outFinal[t]
// ---------------------------------------------------------------------------
__global__ __launch_bounds__(256) void outred_kernel(
    const float* __restrict__ opart,
    const float* __restrict__ b2,   // [E][D]
    const TokRec* __restrict__ rec,
    const int* __restrict__ heavyCount,
    const int* __restrict__ heavyList,
    float* __restrict__ outFinal)
{
    int cnt = *heavyCount; if (cnt > HEAVY_CAP) cnt = HEAVY_CAP;
    const int slot = blockIdx.x;
    if (slot >= cnt) return;
    const int t = heavyList[slot];
    const TokRec r = rec[t];
    const int d = threadIdx.x * 4;

    const float* p0b = opart + ((size_t)(slot * 2 + 0)) * BCH * D;
    const float* p1b = opart + ((size_t)(slot * 2 + 1)) * BCH * D;

    float4 s0 = make_float4(0.f, 0.f, 0.f, 0.f);
    float4 s1 = make_float4(0.f, 0.f, 0.f, 0.f);
#pragma unroll 8
    for (int c = 0; c < BCH; ++c) {
        s0 = f4_add(s0, *reinterpret_cast<const float4*>(p0b + (size_t)c * D + d));
        s1 = f4_add(s1, *reinterpret_cast<const float4*>(p1b + (size_t)c * D + d));
    }
    const float4 bb0 = *reinterpret_cast<const float4*>(b2 + (size_t)r.i0 * D + d);
    const float4 bb1 = *reinterpret_cast<const float4*>(b2 + (size_t)r.i1 * D + d);
    float4 v;
    v.x = r.p0 * (s0.x + bb0.x) + r.p1 * (s1.x + bb1.x);
    v.y = r.p0 * (s0.y + bb0.y) + r.p1 * (s1.y + bb1.y);
    v.z = r.p0 * (s0.z + bb0.z) + r.p1 * (s1.z + bb1.z);
    v.w = r.p0 * (s0.w + bb0.w) + r.p1 * (s1.w + bb1.w);
    *reinterpret_cast<float4*>(outFinal + (size_t)t * D + d) = v;
}

// ---------------------------------------------------------------------------
extern "C" void kernel_launch(void* const* d_in, const int* in_sizes, int n_in,
                              void* d_out, int out_size, void* d_ws, size_t ws_size,
                              hipStream_t stream)
{
    const float* x      = (const float*)d_in[0];
    const float* gate_w = (const float*)d_in[1];
    const float* gate_b = (const float*)d_in[2];
    const float* w1     = (const float*)d_in[3];
    const float* b1     = (const float*)d_in[4];
    const float* w2     = (const float*)d_in[5];
    const float* b2     = (const float*)d_in[6];
    const float* noise  = (const float*)d_in[7];

    float* outFinal = (float*)d_out;
    float* outTopi  = outFinal + (size_t)NTOK * D;
    float* outAux   = outTopi + (size_t)NTOK * K2;

    char* ws = (char*)d_ws;
    size_t off = 0;
    int* heavyCount = (int*)(ws + off);            off += 64;
    int* expCnt     = (int*)(ws + off);            off += 64;
    int* heavyList  = (int*)(ws + off);            off += 128;
    int* expList    = (int*)(ws + off);            off += sizeof(int) * E * 64;
    off = (off + 255) & ~(size_t)255;
    TokRec* rec = (TokRec*)(ws + off);             off += sizeof(TokRec) * NTOK;
    float* usagePartial = (float*)(ws + off);      off += sizeof(float) * (NTOK / 4) * E;
    float* z = (float*)(ws + off);                 off += sizeof(float) * E * D;
    off = (off + 255) & ~(size_t)255;
    float* hpart = (float*)(ws + off);             off += sizeof(float) * 2 * HEAVY_CAP * ACH * H;
    float* opart = (float*)(ws + off);             off += sizeof(float) * 2 * HEAVY_CAP * BCH * D;

    z_kernel<<<E, 256, 0, stream>>>(b1, w2, b2, z, heavyCount, expCnt);
    gate_kernel<<<NTOK / 4, 256, 0, stream>>>(x, gate_w, gate_b, noise, z,
                                              outTopi, outFinal,
                                              rec, heavyCount, heavyList, HEAVY_CAP,
                                              usagePartial, expCnt, expList);
    aux_kernel<<<1, 256, 0, stream>>>(usagePartial, NTOK / 4, outAux);
    heavyA_kernel<<<dim3(E, ACH), 256, 0, stream>>>(
        x, w1, heavyList, expCnt, expList, hpart);
    heavyB_kernel<<<dim3(E, BCH), 256, 0, stream>>>(
        hpart, w2, b1, rec, heavyList, expCnt, expList, opart);
    outred_kernel<<<HEAVY_CAP, 256, 0, stream>>>(
        opart, b2, rec, heavyCount, heavyList, outFinal);
}